// Round 6
// baseline (606.156 us; speedup 1.0000x reference)
//
#include <hip/hip_runtime.h>

typedef unsigned short u16;
typedef unsigned int u32;

#define BB 64
#define FF 4096
#define DD 192
#define HH 768

typedef __attribute__((ext_vector_type(8))) __bf16 bf16x8;
typedef __attribute__((ext_vector_type(4))) float f32x4;

__device__ __forceinline__ float bf2f(u32 u) {
  union { u32 i; float f; } x; x.i = u << 16; return x.f;
}
__device__ __forceinline__ u16 f2bf(float f) {
  __bf16 h = (__bf16)f;
  return __builtin_bit_cast(u16, h);
}
__device__ __forceinline__ u32 pk2bf(float a, float b) {
  return (u32)f2bf(a) | ((u32)f2bf(b) << 16);
}
__device__ __forceinline__ float sigm(float x) { return 1.f / (1.f + __expf(-x)); }

// ---------------------------------------------------------------------------
// Prep: WmodT[n][e] = g[e]*W[e][n] (bf16), s1[n]=sum g*W (bf16-rounded), s0[n]=b@W.
// ---------------------------------------------------------------------------
__global__ void prep_wmod(const float* __restrict__ Wk, const float* __restrict__ Wv,
                          const float* __restrict__ g, const float* __restrict__ bb,
                          u16* __restrict__ wmodT, float* __restrict__ s1,
                          float* __restrict__ s0) {
  int n = blockIdx.x * 64 + threadIdx.x;  // 0..383
  const float* W = (n < DD) ? Wk : Wv;
  int col = (n < DD) ? n : n - DD;
  float a1 = 0.f, a0 = 0.f;
  for (int e = 0; e < DD; ++e) {
    float w = W[e * DD + col];
    u16 h = f2bf(g[e] * w);
    wmodT[n * DD + e] = h;
    a1 += bf2f(h);
    a0 += bb[e] * w;
  }
  s1[n] = a1; s0[n] = a0;
}

// Pack GRU/MLP weights to bf16 e-pairs: dst[((g*E2+e/2)*N + n)*2 + (e&1)].
__global__ void prep_packw(const float* __restrict__ Wih, const float* __restrict__ Whh,
                           const float* __restrict__ W1, const float* __restrict__ W2,
                           u16* __restrict__ pWih, u16* __restrict__ pWhh,
                           u16* __restrict__ pW1, u16* __restrict__ pW2) {
  int which = blockIdx.y;
  int total, N, E;
  const float* src; u16* dst; int srcEmajor;
  if (which < 2) { total = 3 * 576 * 192; N = 576; E = 192; srcEmajor = 0;
                   src = which ? Whh : Wih; dst = which ? pWhh : pWih; }
  else if (which == 2) { total = 3 * 192 * 768; N = 768; E = 192; srcEmajor = 1;
                         src = W1; dst = pW1; }
  else { total = 3 * 768 * 192; N = 192; E = 768; srcEmajor = 1; src = W2; dst = pW2; }
  for (int idx = blockIdx.x * 256 + threadIdx.x; idx < total; idx += gridDim.x * 256) {
    int g = idx / (N * E), rem = idx % (N * E);
    int n, e;
    if (srcEmajor) { e = rem / N; n = rem % N; }    // src[g][e][n]
    else { n = rem / E; e = rem % E; }              // src[g][n][e]
    dst[((g * (E / 2) + (e >> 1)) * N + n) * 2 + (e & 1)] = f2bf(src[idx]);
  }
}

// ---------------------------------------------------------------------------
// Projection v4: pipelined.  Block = 256 thr (4 waves); 4 consecutive 32-token
// tiles per block with register prefetch of tile t+1 issued between the
// staging barrier and the MFMA phase of tile t (HBM latency hidden).
// Wave = one N-quarter (96 cols): w0,w1 -> k; w2,w3 -> v.
// kc_: [Tg][u(24)][tok16][8dims] bf16.  vc_: PV B-frag granules.
// k transpose via per-wave padded Ctile (no cross-wave barrier).
// ---------------------------------------------------------------------------
__global__ __launch_bounds__(256, 4) void proj_kernel(
    const float* __restrict__ feat, const u16* __restrict__ wmodT,
    const float* __restrict__ s1v, const float* __restrict__ s0v,
    u16* __restrict__ kc_, u16* __restrict__ vc_) {
  __shared__ __align__(16) u16 Atile[32 * 192];       // 12.3 KB swizzled bf16
  __shared__ __align__(16) char Ctile[2][32 * 208];   // 13.3 KB, per-k-wave
  __shared__ float stats[64];                         // (mu, rstd) per token
  int tid = threadIdx.x;
  int w = tid >> 6, lane = tid & 63;
  int l15 = lane & 15, l4 = lane >> 4;
  int r = w * 8 + (lane >> 3), p = lane & 7;          // staging: row r, slice p
  long T0 = (long)blockIdx.x * 4;

  float4 cur[6], nxt[6];
  {
    const float4* src = (const float4*)(feat + (T0 * 32 + r) * DD);
    #pragma unroll
    for (int i = 0; i < 6; ++i) cur[i] = src[i * 8 + p];
  }

  #pragma unroll
  for (int t = 0; t < 4; ++t) {
    long T = T0 + t;
    // ---- stage cur -> Atile (swizzled) + LN stats ----
    {
      float s = 0.f, s2 = 0.f;
      #pragma unroll
      for (int i = 0; i < 6; ++i) {
        float4 v = cur[i];
        s += v.x + v.y + v.z + v.w;
        s2 += v.x * v.x + v.y * v.y + v.z * v.z + v.w * v.w;
        int fidx = i * 8 + p;                 // float4 index within row, 0..47
        int u = fidx >> 1, half = fidx & 1;
        uint2 pk;
        pk.x = pk2bf(v.x, v.y);
        pk.y = pk2bf(v.z, v.w);
        *(uint2*)((char*)Atile + r * 384 + ((u ^ (r & 7)) << 4) + half * 8) = pk;
      }
      s += __shfl_xor(s, 1); s2 += __shfl_xor(s2, 1);
      s += __shfl_xor(s, 2); s2 += __shfl_xor(s2, 2);
      s += __shfl_xor(s, 4); s2 += __shfl_xor(s2, 4);
      if (p == 0) {
        float mu = s * (1.f / 192.f);
        stats[r * 2] = mu;
        stats[r * 2 + 1] = rsqrtf(s2 * (1.f / 192.f) - mu * mu + 1e-5f);
      }
    }
    __syncthreads();
    // ---- prefetch tile t+1 into registers (lands under MFMA+epilogue) ----
    if (t < 3) {
      const float4* src = (const float4*)(feat + ((T + 1) * 32 + r) * DD);
      #pragma unroll
      for (int i = 0; i < 6; ++i) nxt[i] = src[i * 8 + p];
    }
    // ---- MFMA: wave w handles cols w*96 .. w*96+95 ----
    f32x4 acc[2][6];
    #pragma unroll
    for (int a = 0; a < 2; ++a)
      #pragma unroll
      for (int b2 = 0; b2 < 6; ++b2) acc[a][b2] = (f32x4){0.f, 0.f, 0.f, 0.f};
    #pragma unroll
    for (int kk = 0; kk < 6; ++kk) {
      bf16x8 afr[2];
      #pragma unroll
      for (int mt = 0; mt < 2; ++mt) {
        int row = mt * 16 + l15;
        int u = kk * 4 + l4;
        afr[mt] = *(bf16x8*)((char*)Atile + row * 384 + ((u ^ (row & 7)) << 4));
      }
      #pragma unroll
      for (int nt = 0; nt < 6; ++nt) {
        int col = w * 96 + nt * 16 + l15;
        bf16x8 bfr = *(const bf16x8*)(wmodT + col * DD + kk * 32 + l4 * 8);
        #pragma unroll
        for (int mt = 0; mt < 2; ++mt)
          acc[mt][nt] = __builtin_amdgcn_mfma_f32_16x16x32_bf16(afr[mt], bfr,
                                                                acc[mt][nt], 0, 0, 0);
      }
    }
    // ---- epilogue ----
    int bidx = (int)(T >> 7);
    int f0 = ((int)T & 127) * 32;
    if (w < 2) {
      // k: LN-fold, transpose through per-wave padded Ctile, coalesced store
      char* ct = Ctile[w];
      #pragma unroll
      for (int nt = 0; nt < 6; ++nt) {
        int c = nt * 16 + l15;                 // local col 0..95
        float s1c = s1v[w * 96 + c], s0c = s0v[w * 96 + c];
        #pragma unroll
        for (int mt = 0; mt < 2; ++mt) {
          #pragma unroll
          for (int j = 0; j < 4; ++j) {
            int row = mt * 16 + l4 * 4 + j;
            float mu = stats[row * 2], rstd = stats[row * 2 + 1];
            u16 hv = f2bf(rstd * (acc[mt][nt][j] - mu * s1c) + s0c);
            *(u16*)(ct + row * 208 + ((c >> 3) << 4) + (c & 7) * 2) = hv;
          }
        }
      }
      asm volatile("s_waitcnt lgkmcnt(0)" ::: "memory");  // wave-local LDS drain
      #pragma unroll
      for (int it = 0; it < 6; ++it) {
        int fi = it * 64 + lane;
        int tau = fi & 15, g = (fi >> 4) % 12, tt = fi / 192;
        uint4 val = *(uint4*)(ct + (tt * 16 + tau) * 208 + g * 16);
        *(uint4*)(kc_ + ((T * 2 + tt) * 24 + w * 12 + g) * 128 + tau * 8) = val;
      }
    } else {
      // v: shfl-pack 8-token granules, direct global store
      #pragma unroll
      for (int nt = 0; nt < 6; ++nt) {
        int col = (w - 2) * 96 + nt * 16 + l15;   // v dim 0..191
        float s1c = s1v[col + 192], s0c = s0v[col + 192];
        int ntg = col >> 4;
        #pragma unroll
        for (int mt = 0; mt < 2; ++mt) {
          int tl = mt * 16 + l4 * 4;
          int r0 = tl, r1 = tl + 1, r2 = tl + 2, r3 = tl + 3;
          uint2 pk;
          pk.x = pk2bf(stats[r0 * 2 + 1] * (acc[mt][nt][0] - stats[r0 * 2] * s1c) + s0c,
                       stats[r1 * 2 + 1] * (acc[mt][nt][1] - stats[r1 * 2] * s1c) + s0c);
          pk.y = pk2bf(stats[r2 * 2 + 1] * (acc[mt][nt][2] - stats[r2 * 2] * s1c) + s0c,
                       stats[r3 * 2 + 1] * (acc[mt][nt][3] - stats[r3 * 2] * s1c) + s0c);
          u32 ox = __shfl_xor((int)pk.x, 16);
          u32 oy = __shfl_xor((int)pk.y, 16);
          if ((l4 & 1) == 0) {
            int t0 = f0 + tl;                  // granule start (multiple of 8)
            int g32 = t0 >> 5;
            int l4f = (t0 >> 3) & 3;
            uint4 val = {pk.x, pk.y, ox, oy};
            *(uint4*)(vc_ + ((((long)bidx * 128 + g32) * 12 + ntg) * 64 + l4f * 16 +
                             (col & 15)) * 8) = val;
          }
        }
      }
    }
    __syncthreads();   // Atile/stats safe to overwrite next iteration
    if (t < 3) {
      #pragma unroll
      for (int i = 0; i < 6; ++i) cur[i] = nxt[i];
    }
  }
}

// ---------------------------------------------------------------------------
// q projection: q = LN(slots) @ Wq * scale.  One wave per (b,k).
// Also zeroes upd/asum_cur/cacc_cur (replaces 3 hipMemsetAsync launches).
// ---------------------------------------------------------------------------
__global__ __launch_bounds__(64) void qproj_kernel(
    const float* __restrict__ slots, const float* __restrict__ Wq,
    const float* __restrict__ g, const float* __restrict__ bb,
    float* __restrict__ qbuf, float* __restrict__ upd,
    float* __restrict__ asum_cur, float* __restrict__ cacc_cur) {
  __shared__ float ln[192];
  int bk = blockIdx.x;
  int lane = threadIdx.x;
  {
    int gtid = bk * 64 + lane;
    float4 z = {0.f, 0.f, 0.f, 0.f};
    if (gtid < 24576) ((float4*)upd)[gtid] = z;
    else if (gtid < 24576 + 128) ((float4*)asum_cur)[gtid - 24576] = z;
    else if (gtid < 24576 + 384) ((float4*)cacc_cur)[gtid - 24704] = z;
  }
  const float* x = slots + bk * DD;
  float v0 = x[lane], v1 = x[lane + 64], v2 = x[lane + 128];
  float s = v0 + v1 + v2, s2 = v0 * v0 + v1 * v1 + v2 * v2;
  #pragma unroll
  for (int m = 1; m < 64; m <<= 1) { s += __shfl_xor(s, m); s2 += __shfl_xor(s2, m); }
  float mu = s * (1.f / 192.f);
  float rstd = rsqrtf(s2 * (1.f / 192.f) - mu * mu + 1e-5f);
  ln[lane]       = (v0 - mu) * rstd * g[lane]       + bb[lane];
  ln[lane + 64]  = (v1 - mu) * rstd * g[lane + 64]  + bb[lane + 64];
  ln[lane + 128] = (v2 - mu) * rstd * g[lane + 128] + bb[lane + 128];
  __syncthreads();
  float a0 = 0.f, a1 = 0.f, a2 = 0.f;
  for (int e = 0; e < DD; ++e) {
    float le = ln[e];
    a0 += le * Wq[e * DD + lane];
    a1 += le * Wq[e * DD + lane + 64];
    a2 += le * Wq[e * DD + lane + 128];
  }
  const float scale = 0.07216878364870323f;  // 192^-0.5
  qbuf[bk * DD + lane]       = a0 * scale;
  qbuf[bk * DD + lane + 64]  = a1 * scale;
  qbuf[bk * DD + lane + 128] = a2 * scale;
}

// ---------------------------------------------------------------------------
// Fused attention + update: QK^T (+bias) -> softmax over 8 -> attn to LDS ->
// PV MFMA -> atomicAdd partial updates.  grid (B, 16): 256 tokens per block.
// ---------------------------------------------------------------------------
__global__ __launch_bounds__(256) void attnupd_kernel(
    const u16* __restrict__ kc_, const u16* __restrict__ vc_,
    const float* __restrict__ qbuf,
    const float* __restrict__ asum_prev, const float* __restrict__ cacc_prev,
    float* __restrict__ upd, float* __restrict__ asum_cur,
    float* __restrict__ cacc_cur, int have_bias) {
  __shared__ __align__(16) u16 qlds[16 * 192];
  __shared__ __align__(16) u16 attn_lds[16 * 256];   // [slot][token], XOR-swizzled
  int b = blockIdx.x;
  int chunk = blockIdx.y * 256;
  int tid = threadIdx.x;
  if (tid < 192) {
    int s = tid / 24, u = tid % 24;
    const float* qp = qbuf + (b * 8 + s) * DD + u * 8;
    uint4 p;
    p.x = pk2bf(qp[0], qp[1]);
    p.y = pk2bf(qp[2], qp[3]);
    p.z = pk2bf(qp[4], qp[5]);
    p.w = pk2bf(qp[6], qp[7]);
    *(uint4*)((char*)qlds + s * 384 + ((u ^ (s & 7)) << 4)) = p;
  } else {
    int t2 = tid - 192;
    #pragma unroll
    for (int i = 0; i < 3; ++i) {
      int idx = t2 * 3 + i;      // 192 units of q rows 8..15
      int s = 8 + idx / 24, u = idx % 24;
      *(uint4*)((char*)qlds + s * 384 + ((u ^ (s & 7)) << 4)) = (uint4){0, 0, 0, 0};
    }
    #pragma unroll
    for (int i = 0; i < 4; ++i)
      *(uint4*)((char*)attn_lds + 4096 + (t2 * 4 + i) * 16) = (uint4){0, 0, 0, 0};
  }
  __syncthreads();
  int w = tid >> 6, lane = tid & 63;
  int l15 = lane & 15, l4 = lane >> 4;
  bf16x8 qfr[6];
  #pragma unroll
  for (int kk = 0; kk < 6; ++kk) {
    int u = kk * 4 + l4;
    qfr[kk] = *(bf16x8*)((char*)qlds + l15 * 384 + ((u ^ (l15 & 7)) << 4));
  }
  float ax[4], ay[4], c0[4];
  #pragma unroll
  for (int j = 0; j < 4; ++j) {
    int s = l4 * 4 + j;
    if (have_bias && s < 8) {
      float inv = 1.f / (asum_prev[b * 8 + s] + 1e-8f);
      float cx = cacc_prev[(b * 8 + s) * 2] * inv;
      float cy = cacc_prev[(b * 8 + s) * 2 + 1] * inv;
      ax[j] = 16.f * cx; ay[j] = 16.f * cy; c0[j] = -8.f * (cx * cx + cy * cy);
    } else { ax[j] = 0.f; ay[j] = 0.f; c0[j] = 0.f; }
  }
  float pa[4], px[4], py[4];
  #pragma unroll
  for (int j = 0; j < 4; ++j) { pa[j] = 0.f; px[j] = 0.f; py[j] = 0.f; }
  for (int tile = w; tile < 16; tile += 4) {
    int t0 = chunk + tile * 16;
    long Tg = (long)b * 256 + (t0 >> 4);
    const u16* kp = kc_ + (Tg * 24 + l4) * 128 + l15 * 8;
    f32x4 acc = (f32x4){0.f, 0.f, 0.f, 0.f};
    #pragma unroll
    for (int kk = 0; kk < 6; ++kk) {
      bf16x8 bfr = *(const bf16x8*)(kp + kk * 512);
      acc = __builtin_amdgcn_mfma_f32_16x16x32_bf16(qfr[kk], bfr, acc, 0, 0, 0);
    }
    int t = t0 + l15;
    float x = -1.f + (float)(t & 63) * (2.f / 63.f);
    float y = -1.f + (float)(t >> 6) * (2.f / 63.f);
    float m8r2 = -8.f * (x * x + y * y);
    float d4[4];
    #pragma unroll
    for (int j = 0; j < 4; ++j)
      d4[j] = acc[j] + (have_bias ? (ax[j] * x + ay[j] * y + c0[j] + m8r2) : 0.f);
    float o4[4];
    #pragma unroll
    for (int j = 0; j < 4; ++j) o4[j] = __shfl_xor(d4[j], 16);
    float mx = fmaxf(fmaxf(fmaxf(d4[0], d4[1]), fmaxf(d4[2], d4[3])),
                     fmaxf(fmaxf(o4[0], o4[1]), fmaxf(o4[2], o4[3])));
    float e4[4];
    float sum = 0.f;
    #pragma unroll
    for (int j = 0; j < 4; ++j) { e4[j] = __expf(d4[j] - mx); sum += e4[j]; }
    #pragma unroll
    for (int j = 0; j < 4; ++j) sum += __expf(o4[j] - mx);
    float inv = 1.f / sum;
    if (l4 < 2) {
      int tl = tile * 16 + l15;
      #pragma unroll
      for (int j = 0; j < 4; ++j) {
        float a = e4[j] * inv;
        int s = l4 * 4 + j;
        *(u16*)((char*)attn_lds + ((s * 512 + tl * 2) ^ ((s & 7) << 4))) = f2bf(a);
        pa[j] += a; px[j] += a * x; py[j] += a * y;
      }
    }
  }
  #pragma unroll
  for (int m = 1; m < 16; m <<= 1) {
    #pragma unroll
    for (int j = 0; j < 4; ++j) {
      pa[j] += __shfl_xor(pa[j], m);
      px[j] += __shfl_xor(px[j], m);
      py[j] += __shfl_xor(py[j], m);
    }
  }
  if (l15 == 0 && l4 < 2) {
    #pragma unroll
    for (int j = 0; j < 4; ++j) {
      int s = l4 * 4 + j;
      atomicAdd(&asum_cur[b * 8 + s], pa[j]);
      atomicAdd(&cacc_cur[(b * 8 + s) * 2], px[j]);
      atomicAdd(&cacc_cur[(b * 8 + s) * 2 + 1], py[j]);
    }
  }
  __syncthreads();
  int g32base = chunk >> 5;
  #pragma unroll
  for (int ni = 0; ni < 3; ++ni) {
    int nt = w * 3 + ni;
    f32x4 acc = (f32x4){0.f, 0.f, 0.f, 0.f};
    const u16* vp = vc_ + ((((long)b * 128 + g32base) * 12 + nt) * 64 + l4 * 16 + l15) * 8;
    #pragma unroll
    for (int gl = 0; gl < 8; ++gl) {
      int tl0 = gl * 32 + l4 * 8;
      bf16x8 afr = *(bf16x8*)((char*)attn_lds + ((l15 * 512 + tl0 * 2) ^ ((l15 & 7) << 4)));
      bf16x8 bfr = *(const bf16x8*)(vp + gl * 12 * 64 * 8);
      acc = __builtin_amdgcn_mfma_f32_16x16x32_bf16(afr, bfr, acc, 0, 0, 0);
    }
    if (l4 < 2) {
      #pragma unroll
      for (int j = 0; j < 4; ++j) {
        int s = l4 * 4 + j;
        atomicAdd(&upd[((long)b * 8 + s) * DD + nt * 16 + l15], acc[j]);
      }
    }
  }
}

// ---------------------------------------------------------------------------
// GRU + LN + MLP.  768 threads (12 waves), column-parallel phases, bf16 weights.
// grid (B, 4): y0: g0 slot0 (M=1); y1: g2 slot7 (M=1); y2: g1 slots1-3; y3: g1 slots4-6.
// ---------------------------------------------------------------------------
template <int M>
__device__ void gru_body(int b0, int g, int srow,
                         float* u_l, float* h_l, float* gi_l, float* gh_l,
                         float* hn_l, float* ln_l, float* x1_l, float* out_l, float* st,
                         const float* __restrict__ upd, const float* __restrict__ asum,
                         const float* __restrict__ sin_,
                         const u16* __restrict__ pWih, const u16* __restrict__ pWhh,
                         const float* __restrict__ bih, const float* __restrict__ bhh,
                         const float* __restrict__ mlng, const float* __restrict__ mlnb,
                         const u16* __restrict__ pW1, const float* __restrict__ b1,
                         const u16* __restrict__ pW2, const float* __restrict__ b2,
                         float* __restrict__ sout) {
  int tid = threadIdx.x;
  for (int idx = tid; idx < M * 192; idx += 768) {
    int row = idx / 192, d = idx % 192;
    int gr = b0 * 8 + srow + row;
    float inv = 1.f / (asum[gr] + 1e-8f);
    u_l[row * 192 + d] = upd[gr * DD + d] * inv;
    h_l[row * 192 + d] = sin_[gr * DD + d];
  }
  __syncthreads();
  if (tid < 576) {
    int c = tid;
    const u16* wih = pWih + (size_t)g * 96 * 1152 + c * 2;
    const u16* whh = pWhh + (size_t)g * 96 * 1152 + c * 2;
    float ai[M], ah[M];
    #pragma unroll
    for (int r = 0; r < M; ++r) { ai[r] = 0.f; ah[r] = 0.f; }
    #pragma unroll 4
    for (int e2 = 0; e2 < 96; ++e2) {
      u32 wi = *(const u32*)(wih + e2 * 1152);
      u32 wh = *(const u32*)(whh + e2 * 1152);
      float wi0 = bf2f(wi & 0xffffu), wi1 = bf2f(wi >> 16);
      float wh0 = bf2f(wh & 0xffffu), wh1 = bf2f(wh >> 16);
      #pragma unroll
      for (int r = 0; r < M; ++r) {
        ai[r] += wi0 * u_l[r * 192 + e2 * 2] + wi1 * u_l[r * 192 + e2 * 2 + 1];
        ah[r] += wh0 * h_l[r * 192 + e2 * 2] + wh1 * h_l[r * 192 + e2 * 2 + 1];
      }
    }
    #pragma unroll
    for (int r = 0; r < M; ++r) { gi_l[r * 576 + c] = ai[r]; gh_l[r * 576 + c] = ah[r]; }
  }
  __syncthreads();
  if (tid < M * 192) {
    int row = tid / 192, uu = tid % 192;
    const float* bihg = bih + g * 576;
    const float* bhhg = bhh + g * 576;
    float r_ = sigm(gi_l[row * 576 + uu] + bihg[uu] + gh_l[row * 576 + uu] + bhhg[uu]);
    float z_ = sigm(gi_l[row * 576 + 192 + uu] + bihg[192 + uu] +
                    gh_l[row * 576 + 192 + uu] + bhhg[192 + uu]);
    float nn = gi_l[row * 576 + 384 + uu] + bihg[384 + uu] +
               r_ * (gh_l[row * 576 + 384 + uu] + bhhg[384 + uu]);
    float t = 1.f - 2.f / (__expf(2.f * nn) + 1.f);
    hn_l[row * 192 + uu] = (1.f - z_) * t + z_ * h_l[row * 192 + uu];
  }
  __syncthreads();
  {
    int wv = tid >> 6, lane = tid & 63;
    if (wv < M) {
      float v0 = hn_l[wv * 192 + lane], v1 = hn_l[wv * 192 + lane + 64],
            v2 = hn_l[wv * 192 + lane + 128];
      float s = v0 + v1 + v2, sq = v0 * v0 + v1 * v1 + v2 * v2;
      #pragma unroll
      for (int m = 1; m < 64; m <<= 1) { s += __shfl_xor(s, m); sq += __shfl_xor(sq, m); }
      if (lane == 0) {
        float mu = s * (1.f / 192.f);
        st[wv * 2] = mu;
        st[wv * 2 + 1] = rsqrtf(sq * (1.f / 192.f) - mu * mu + 1e-5f);
      }
    }
  }
  __syncthreads();
  if (tid < M * 192) {
    int row = tid / 192, uu = tid % 192;
    ln_l[row * 192 + uu] = (hn_l[row * 192 + uu] - st[row * 2]) * st[row * 2 + 1] *
                               mlng[g * DD + uu] + mlnb[g * DD + uu];
  }
  __syncthreads();
  {
    int c = tid;
    const u16* w1 = pW1 + (size_t)g * 96 * 1536 + c * 2;
    float a[M];
    #pragma unroll
    for (int r = 0; r < M; ++r) a[r] = 0.f;
    #pragma unroll 4
    for (int e2 = 0; e2 < 96; ++e2) {
      u32 wp = *(const u32*)(w1 + e2 * 1536);
      float w0 = bf2f(wp & 0xffffu), w1f = bf2f(wp >> 16);
      #pragma unroll
      for (int r = 0; r < M; ++r)
        a[r] += w0 * ln_l[r * 192 + e2 * 2] + w1f * ln_l[r * 192 + e2 * 2 + 1];
    }
    float bc = b1[g * HH + c];
    #pragma unroll
    for (int r = 0; r < M; ++r) x1_l[r * 768 + c] = fmaxf(a[r] + bc, 0.f);
  }
  if (tid < M * 192) {
    int row = tid / 192, uu = tid % 192;
    out_l[row * 192 + uu] = hn_l[row * 192 + uu] + b2[g * DD + uu];
  }
  __syncthreads();
  {
    int c = tid % 192, ks = tid / 192;
    const u16* w2 = pW2 + (size_t)g * 384 * 384 + c * 2;
    float a[M];
    #pragma unroll
    for (int r = 0; r < M; ++r) a[r] = 0.f;
    #pragma unroll 4
    for (int e2 = ks * 96; e2 < ks * 96 + 96; ++e2) {
      u32 wp = *(const u32*)(w2 + e2 * 384);
      float w0 = bf2f(wp & 0xffffu), w1f = bf2f(wp >> 16);
      #pragma unroll
      for (int r = 0; r < M; ++r)
        a[r] += w0 * x1_l[r * 768 + e2 * 2] + w1f * x1_l[r * 768 + e2 * 2 + 1];
    }
    #pragma unroll
    for (int r = 0; r < M; ++r) atomicAdd(&out_l[r * 192 + c], a[r]);
  }
  __syncthreads();
  if (tid < M * 192) {
    int row = tid / 192, d = tid % 192;
    sout[(b0 * 8 + srow + row) * DD + d] = out_l[row * 192 + d];
  }
}

__global__ __launch_bounds__(768) void gru_kernel(
    const float* __restrict__ upd, const float* __restrict__ asum,
    const float* __restrict__ sin_,
    const u16* __restrict__ pWih, const u16* __restrict__ pWhh,
    const float* __restrict__ bih, const float* __restrict__ bhh,
    const float* __restrict__ mlng, const float* __restrict__ mlnb,
    const u16* __restrict__ pW1, const float* __restrict__ b1,
    const u16* __restrict__ pW2, const float* __restrict__ b2,
    float* __restrict__ sout) {
  __shared__ float u_l[3 * 192], h_l[3 * 192], gi_l[3 * 576], gh_l[3 * 576];
  __shared__ float hn_l[3 * 192], ln_l[3 * 192], x1_l[3 * 768], out_l[3 * 192], st[8];
  int b = blockIdx.x, y = blockIdx.y;
  if (y == 0)
    gru_body<1>(b, 0, 0, u_l, h_l, gi_l, gh_l, hn_l, ln_l, x1_l, out_l, st,
                upd, asum, sin_, pWih, pWhh, bih, bhh, mlng, mlnb, pW1, b1, pW2, b2, sout);
  else if (y == 1)
    gru_body<1>(b, 2, 7, u_l, h_l, gi_l, gh_l, hn_l, ln_l, x1_l, out_l, st,
                upd, asum, sin_, pWih, pWhh, bih, bhh, mlng, mlnb, pW1, b1, pW2, b2, sout);
  else if (y == 2)
    gru_body<3>(b, 1, 1, u_l, h_l, gi_l, gh_l, hn_l, ln_l, x1_l, out_l, st,
                upd, asum, sin_, pWih, pWhh, bih, bhh, mlng, mlnb, pW1, b1, pW2, b2, sout);
  else
    gru_body<3>(b, 1, 4, u_l, h_l, gi_l, gh_l, hn_l, ln_l, x1_l, out_l, st,
                upd, asum, sin_, pWih, pWhh, bih, bhh, mlng, mlnb, pW1, b1, pW2, b2, sout);
}

// ---------------------------------------------------------------------------
extern "C" void kernel_launch(void* const* d_in, const int* in_sizes, int n_in,
                              void* d_out, int out_size, void* d_ws, size_t ws_size,
                              hipStream_t stream) {
  const float* feat = (const float*)d_in[0];
  const float* slots = (const float*)d_in[1];
  const float* Wk = (const float*)d_in[2];
  const float* Wv = (const float*)d_in[3];
  const float* Wq = (const float*)d_in[4];
  const float* lfg = (const float*)d_in[5];
  const float* lfb = (const float*)d_in[6];
  const float* lsg = (const float*)d_in[7];
  const float* lsb = (const float*)d_in[8];
  const float* gWih = (const float*)d_in[9];
  const float* gWhh = (const float*)d_in[10];
  const float* gbih = (const float*)d_in[11];
  const float* gbhh = (const float*)d_in[12];
  const float* mlng = (const float*)d_in[13];
  const float* mlnb = (const float*)d_in[14];
  const float* W1 = (const float*)d_in[15];
  const float* b1 = (const float*)d_in[16];
  const float* W2 = (const float*)d_in[17];
  const float* b2 = (const float*)d_in[18];
  float* out = (float*)d_out;

  char* ws = (char*)d_ws;
  size_t off = 0;
  auto alloc = [&](size_t bytes) {
    void* p = ws + off;
    off += (bytes + 255) & ~(size_t)255;
    return p;
  };
  u16* kc_    = (u16*)alloc((size_t)BB * FF * DD * 2);
  u16* vc_    = (u16*)alloc((size_t)BB * DD * FF * 2);
  float* qbuf = (float*)alloc((size_t)BB * 8 * DD * 4);
  float* upd  = (float*)alloc((size_t)BB * 8 * DD * 4);
  float* slA  = (float*)alloc((size_t)BB * 8 * DD * 4);
  float* slB  = (float*)alloc((size_t)BB * 8 * DD * 4);
  float* asum0 = (float*)alloc(BB * 8 * 4);
  float* asum1 = (float*)alloc(BB * 8 * 4);
  float* cacc0 = (float*)alloc(BB * 8 * 2 * 4);
  float* cacc1 = (float*)alloc(BB * 8 * 2 * 4);
  u16* wmodT  = (u16*)alloc(384 * DD * 2);
  float* s1   = (float*)alloc(384 * 4);
  float* s0   = (float*)alloc(384 * 4);
  u16* pWih   = (u16*)alloc((size_t)3 * 576 * DD * 2);
  u16* pWhh   = (u16*)alloc((size_t)3 * 576 * DD * 2);
  u16* pW1    = (u16*)alloc((size_t)3 * DD * HH * 2);
  u16* pW2    = (u16*)alloc((size_t)3 * HH * DD * 2);

  prep_wmod<<<6, 64, 0, stream>>>(Wk, Wv, lfg, lfb, wmodT, s1, s0);
  prep_packw<<<dim3(432, 4), 256, 0, stream>>>(gWih, gWhh, W1, W2, pWih, pWhh, pW1, pW2);
  proj_kernel<<<2048, 256, 0, stream>>>(feat, wmodT, s1, s0, kc_, vc_);

  const float* sin_ = slots;
  float* souts[3] = {slA, slB, out};
  float* asums[2] = {asum0, asum1};
  float* caccs[2] = {cacc0, cacc1};
  for (int it = 0; it < 3; ++it) {
    int cur = it & 1, prev = cur ^ 1;
    qproj_kernel<<<BB * 8, 64, 0, stream>>>(sin_, Wq, lsg, lsb, qbuf,
                                            upd, asums[cur], caccs[cur]);
    attnupd_kernel<<<dim3(BB, 16), 256, 0, stream>>>(kc_, vc_, qbuf, asums[prev],
                                                     caccs[prev], upd, asums[cur],
                                                     caccs[cur], it > 0 ? 1 : 0);
    gru_kernel<<<dim3(BB, 4), 768, 0, stream>>>(upd, asums[cur], sin_, pWih, pWhh,
                                                gbih, gbhh, mlng, mlnb, pW1, b1, pW2, b2,
                                                souts[it]);
    sin_ = souts[it];
  }
}

// Round 7
// 519.190 us; speedup vs baseline: 1.1675x; 1.1675x over previous
//
#include <hip/hip_runtime.h>

typedef unsigned short u16;
typedef unsigned int u32;

#define BB 64
#define FF 4096
#define DD 192
#define HH 768

typedef __attribute__((ext_vector_type(8))) __bf16 bf16x8;
typedef __attribute__((ext_vector_type(4))) float f32x4;

__device__ __forceinline__ float bf2f(u32 u) {
  union { u32 i; float f; } x; x.i = u << 16; return x.f;
}
__device__ __forceinline__ u16 f2bf(float f) {
  __bf16 h = (__bf16)f;
  return __builtin_bit_cast(u16, h);
}
__device__ __forceinline__ u32 pk2bf(float a, float b) {
  return (u32)f2bf(a) | ((u32)f2bf(b) << 16);
}
__device__ __forceinline__ float sigm(float x) { return 1.f / (1.f + __expf(-x)); }

// ---------------------------------------------------------------------------
// Prep: Wvm[e][d] = g[e]*Wv[e][d] (f32), s0v[d] = b@Wv, s0k[d] = b@Wk.
// ---------------------------------------------------------------------------
__global__ void prep_vw(const float* __restrict__ Wk, const float* __restrict__ Wv,
                        const float* __restrict__ g, const float* __restrict__ bb,
                        float* __restrict__ Wvm, float* __restrict__ s0v,
                        float* __restrict__ s0k) {
  int d = threadIdx.x;  // 0..191
  float av = 0.f, ak = 0.f;
  for (int e = 0; e < DD; ++e) {
    float wv = Wv[e * DD + d];
    Wvm[e * DD + d] = g[e] * wv;
    av += bb[e] * wv;
    ak += bb[e] * Wk[e * DD + d];
  }
  s0v[d] = av; s0k[d] = ak;
}

// Pack GRU/MLP weights to bf16 e-pairs: dst[((g*E2+e/2)*N + n)*2 + (e&1)].
__global__ void prep_packw(const float* __restrict__ Wih, const float* __restrict__ Whh,
                           const float* __restrict__ W1, const float* __restrict__ W2,
                           u16* __restrict__ pWih, u16* __restrict__ pWhh,
                           u16* __restrict__ pW1, u16* __restrict__ pW2) {
  int which = blockIdx.y;
  int total, N, E;
  const float* src; u16* dst; int srcEmajor;
  if (which < 2) { total = 3 * 576 * 192; N = 576; E = 192; srcEmajor = 0;
                   src = which ? Whh : Wih; dst = which ? pWhh : pWih; }
  else if (which == 2) { total = 3 * 192 * 768; N = 768; E = 192; srcEmajor = 1;
                         src = W1; dst = pW1; }
  else { total = 3 * 768 * 192; N = 192; E = 768; srcEmajor = 1; src = W2; dst = pW2; }
  for (int idx = blockIdx.x * 256 + threadIdx.x; idx < total; idx += gridDim.x * 256) {
    int g = idx / (N * E), rem = idx % (N * E);
    int n, e;
    if (srcEmajor) { e = rem / N; n = rem % N; }    // src[g][e][n]
    else { n = rem / E; e = rem % E; }              // src[g][n][e]
    dst[((g * (E / 2) + (e >> 1)) * N + n) * 2 + (e & 1)] = f2bf(src[idx]);
  }
}

// ---------------------------------------------------------------------------
// fconv: stream feat f32 -> bf16 in two layouts + per-token LN stats.
// fb: QK granules [Tg][u(24)][tau16][8dims].  fd: PV granules
// [((b*128+g32)*12+ntg)*64 + l4f*16 + (d&15)][8toks].  stats[t]={rstd, mu}.
// Block = 64 tokens, 256 thr; thread (r=tid>>2, p=tid&3) owns dims p*48..+47.
// ---------------------------------------------------------------------------
__global__ __launch_bounds__(256) void fconv(const float* __restrict__ feat,
                                             u16* __restrict__ fb, u16* __restrict__ fd,
                                             float2* __restrict__ stats) {
  __shared__ __align__(16) u16 flds[64 * 192];   // token-major bf16 tile
  int tid = threadIdx.x;
  int blk = blockIdx.x;
  int r = tid >> 2, p = tid & 3;
  long t = (long)blk * 64 + r;
  const float4* src = (const float4*)(feat + t * DD) + p * 12;
  float s = 0.f, s2 = 0.f;
  long Tg = t >> 4; int tau = (int)(t & 15);
  #pragma unroll
  for (int i = 0; i < 6; ++i) {
    float4 a = src[i * 2], b = src[i * 2 + 1];
    s += a.x + a.y + a.z + a.w + b.x + b.y + b.z + b.w;
    s2 += a.x * a.x + a.y * a.y + a.z * a.z + a.w * a.w +
          b.x * b.x + b.y * b.y + b.z * b.z + b.w * b.w;
    uint4 v;
    v.x = pk2bf(a.x, a.y); v.y = pk2bf(a.z, a.w);
    v.z = pk2bf(b.x, b.y); v.w = pk2bf(b.z, b.w);
    int u = p * 6 + i;
    *(uint4*)(fb + ((Tg * 24 + u) * 16 + tau) * 8) = v;
    *(uint4*)((char*)flds + r * 384 + p * 96 + i * 16) = v;
  }
  s += __shfl_xor(s, 1); s2 += __shfl_xor(s2, 1);
  s += __shfl_xor(s, 2); s2 += __shfl_xor(s2, 2);
  if (p == 0) {
    float mu = s * (1.f / 192.f);
    float rstd = rsqrtf(s2 * (1.f / 192.f) - mu * mu + 1e-5f);
    stats[t] = make_float2(rstd, mu);
  }
  __syncthreads();
  // fd pass: granule = (8 tokens, 1 dim).  idx -> (tg8 = token-octet, d).
  int b = blk >> 6;
  #pragma unroll
  for (int i = 0; i < 6; ++i) {
    int idx = tid + i * 256;            // 0..1535
    int tg8 = idx / 192, d = idx % 192;
    u16 h[8];
    #pragma unroll
    for (int j = 0; j < 8; ++j) h[j] = flds[(tg8 * 8 + j) * 192 + d];
    uint4 v;
    v.x = (u32)h[0] | ((u32)h[1] << 16);
    v.y = (u32)h[2] | ((u32)h[3] << 16);
    v.z = (u32)h[4] | ((u32)h[5] << 16);
    v.w = (u32)h[6] | ((u32)h[7] << 16);
    int g32 = (blk & 63) * 2 + (tg8 >> 2);
    int l4f = tg8 & 3;
    *(uint4*)(fd + ((((long)b * 128 + g32) * 12 + (d >> 4)) * 64 + l4f * 16 +
                    (d & 15)) * 8) = v;
  }
}

// ---------------------------------------------------------------------------
// q projection + p = g ⊙ (Wk @ q), alpha = sum(bf16(p)), beta = s0k·q.
// One wave per (b,slot).  Also zeroes U/scal_cur (replaces memsets) and
// pbuf rows 8..15 (MFMA padding).
// ---------------------------------------------------------------------------
__global__ __launch_bounds__(64) void qproj_kernel(
    const float* __restrict__ slots, const float* __restrict__ Wq,
    const float* __restrict__ lsg, const float* __restrict__ lsb,
    const float* __restrict__ Wk, const float* __restrict__ lfg,
    const float* __restrict__ s0k,
    u16* __restrict__ pbuf, float* __restrict__ pab,
    float* __restrict__ U, float* __restrict__ scal_cur) {
  __shared__ float ln[192];
  int bk = blockIdx.x;
  int b = bk >> 3, sl = bk & 7;
  int lane = threadIdx.x;
  {
    int gtid = bk * 64 + lane;
    float4 z = {0.f, 0.f, 0.f, 0.f};
    if (gtid < 24576) ((float4*)U)[gtid] = z;
    else if (gtid < 24576 + 512) ((float4*)scal_cur)[gtid - 24576] = z;
  }
  const float* x = slots + bk * DD;
  float v0 = x[lane], v1 = x[lane + 64], v2 = x[lane + 128];
  float s = v0 + v1 + v2, s2 = v0 * v0 + v1 * v1 + v2 * v2;
  #pragma unroll
  for (int m = 1; m < 64; m <<= 1) { s += __shfl_xor(s, m); s2 += __shfl_xor(s2, m); }
  float mu = s * (1.f / 192.f);
  float rstd = rsqrtf(s2 * (1.f / 192.f) - mu * mu + 1e-5f);
  ln[lane]       = (v0 - mu) * rstd * lsg[lane]       + lsb[lane];
  ln[lane + 64]  = (v1 - mu) * rstd * lsg[lane + 64]  + lsb[lane + 64];
  ln[lane + 128] = (v2 - mu) * rstd * lsg[lane + 128] + lsb[lane + 128];
  __syncthreads();
  float a0 = 0.f, a1 = 0.f, a2 = 0.f;
  for (int e = 0; e < DD; ++e) {
    float le = ln[e];
    a0 += le * Wq[e * DD + lane];
    a1 += le * Wq[e * DD + lane + 64];
    a2 += le * Wq[e * DD + lane + 128];
  }
  __syncthreads();
  const float scale = 0.07216878364870323f;  // 192^-0.5
  ln[lane] = a0 * scale; ln[lane + 64] = a1 * scale; ln[lane + 128] = a2 * scale;
  __syncthreads();
  // p_d = lfg[d] * (Wk[d,:] . q);  alpha = sum bf16(p);  beta = s0k . q
  float al = 0.f, be = 0.f;
  u16 pb[3];
  #pragma unroll
  for (int k3 = 0; k3 < 3; ++k3) {
    int d = lane + k3 * 64;
    const float* wr = Wk + (size_t)d * DD;
    float pd = 0.f;
    for (int e = 0; e < DD; ++e) pd += wr[e] * ln[e];
    pd *= lfg[d];
    u16 h = f2bf(pd);
    pb[k3] = h;
    al += bf2f(h);
    be += s0k[d] * ln[d];
  }
  #pragma unroll
  for (int m = 1; m < 64; m <<= 1) { al += __shfl_xor(al, m); be += __shfl_xor(be, m); }
  #pragma unroll
  for (int k3 = 0; k3 < 3; ++k3)
    pbuf[(b * 16 + sl) * DD + lane + k3 * 64] = pb[k3];
  if (lane < 24) *(uint4*)(pbuf + (b * 16 + 8 + sl) * DD + lane * 8) = (uint4){0, 0, 0, 0};
  if (lane == 0) { pab[bk * 2] = al; pab[bk * 2 + 1] = be; }
}

// ---------------------------------------------------------------------------
// Fused attention + update on raw features:
// dots = rstd*(f.p) - rstd*mu*alpha + beta (+bias) -> softmax over 8 ->
// w' = attn*rstd to LDS -> PV MFMA (U += w' f) -> atomics.
// grid (B, 16): 256 tokens per block.  fb/fd granule reads as in prior kernel.
// ---------------------------------------------------------------------------
__global__ __launch_bounds__(256) void attnpv_kernel(
    const u16* __restrict__ fb, const u16* __restrict__ fd,
    const u16* __restrict__ pbuf, const float* __restrict__ pab,
    const float2* __restrict__ stats,
    const float* __restrict__ scal_prev,
    float* __restrict__ U, float* __restrict__ scal_cur, int have_bias) {
  __shared__ __align__(16) u16 plds[16 * 192];
  __shared__ __align__(16) u16 attn_lds[16 * 256];   // [slot][token], XOR-swizzled
  int b = blockIdx.x;
  int chunk = blockIdx.y * 256;
  int tid = threadIdx.x;
  // stage p (swizzled) + zero attn rows 8..15
  #pragma unroll
  for (int i = 0; i < 2; ++i) {
    int g = tid + i * 256;
    if (g < 384) {
      int s = g / 24, u = g % 24;
      uint4 v = *(const uint4*)(pbuf + ((b * 16 + s) * DD + u * 8));
      *(uint4*)((char*)plds + s * 384 + ((u ^ (s & 7)) << 4)) = v;
    }
  }
  *(uint4*)((char*)attn_lds + 4096 + tid * 16) = (uint4){0, 0, 0, 0};
  __syncthreads();
  int w = tid >> 6, lane = tid & 63;
  int l15 = lane & 15, l4 = lane >> 4;
  bf16x8 qfr[6];
  #pragma unroll
  for (int kk = 0; kk < 6; ++kk) {
    int u = kk * 4 + l4;
    qfr[kk] = *(bf16x8*)((char*)plds + l15 * 384 + ((u ^ (l15 & 7)) << 4));
  }
  float ax[4], ay[4], c0[4], av[4], bv[4];
  #pragma unroll
  for (int j = 0; j < 4; ++j) {
    int s = l4 * 4 + j;
    if (s < 8) {
      av[j] = pab[(b * 8 + s) * 2];
      bv[j] = pab[(b * 8 + s) * 2 + 1];
      if (have_bias) {
        float inv = 1.f / (scal_prev[(b * 8 + s) * 4] + 1e-8f);
        float cx = scal_prev[(b * 8 + s) * 4 + 1] * inv;
        float cy = scal_prev[(b * 8 + s) * 4 + 2] * inv;
        ax[j] = 16.f * cx; ay[j] = 16.f * cy; c0[j] = -8.f * (cx * cx + cy * cy);
      } else { ax[j] = 0.f; ay[j] = 0.f; c0[j] = 0.f; }
    } else { av[j] = 0.f; bv[j] = 0.f; ax[j] = 0.f; ay[j] = 0.f; c0[j] = 0.f; }
  }
  float pa[4], px[4], py[4], pg[4];
  #pragma unroll
  for (int j = 0; j < 4; ++j) { pa[j] = 0.f; px[j] = 0.f; py[j] = 0.f; pg[j] = 0.f; }
  for (int tile = w; tile < 16; tile += 4) {
    int t0 = chunk + tile * 16;
    long Tg = (long)b * 256 + (t0 >> 4);
    const u16* kp = fb + (Tg * 24 + l4) * 128 + l15 * 8;
    f32x4 acc = (f32x4){0.f, 0.f, 0.f, 0.f};
    #pragma unroll
    for (int kk = 0; kk < 6; ++kk) {
      bf16x8 bfr = *(const bf16x8*)(kp + kk * 512);
      acc = __builtin_amdgcn_mfma_f32_16x16x32_bf16(qfr[kk], bfr, acc, 0, 0, 0);
    }
    int t = t0 + l15;
    float2 st = stats[((long)b << 12) + t];
    float rstd = st.x, muv = st.y;
    float x = -1.f + (float)(t & 63) * (2.f / 63.f);
    float y = -1.f + (float)(t >> 6) * (2.f / 63.f);
    float m8r2 = -8.f * (x * x + y * y);
    float d4[4];
    #pragma unroll
    for (int j = 0; j < 4; ++j)
      d4[j] = rstd * acc[j] - rstd * muv * av[j] + bv[j] +
              (have_bias ? (ax[j] * x + ay[j] * y + c0[j] + m8r2) : 0.f);
    float o4[4];
    #pragma unroll
    for (int j = 0; j < 4; ++j) o4[j] = __shfl_xor(d4[j], 16);
    float mx = fmaxf(fmaxf(fmaxf(d4[0], d4[1]), fmaxf(d4[2], d4[3])),
                     fmaxf(fmaxf(o4[0], o4[1]), fmaxf(o4[2], o4[3])));
    float e4[4];
    float sum = 0.f;
    #pragma unroll
    for (int j = 0; j < 4; ++j) { e4[j] = __expf(d4[j] - mx); sum += e4[j]; }
    #pragma unroll
    for (int j = 0; j < 4; ++j) sum += __expf(o4[j] - mx);
    float inv = 1.f / sum;
    if (l4 < 2) {
      int tl = tile * 16 + l15;
      #pragma unroll
      for (int j = 0; j < 4; ++j) {
        float a = e4[j] * inv;
        u16 wr = f2bf(a * rstd);
        int s = l4 * 4 + j;
        *(u16*)((char*)attn_lds + ((s * 512 + tl * 2) ^ ((s & 7) << 4))) = wr;
        pa[j] += a; px[j] += a * x; py[j] += a * y;
        pg[j] += bf2f(wr) * muv;
      }
    }
  }
  #pragma unroll
  for (int m = 1; m < 16; m <<= 1) {
    #pragma unroll
    for (int j = 0; j < 4; ++j) {
      pa[j] += __shfl_xor(pa[j], m);
      px[j] += __shfl_xor(px[j], m);
      py[j] += __shfl_xor(py[j], m);
      pg[j] += __shfl_xor(pg[j], m);
    }
  }
  if (l15 == 0 && l4 < 2) {
    #pragma unroll
    for (int j = 0; j < 4; ++j) {
      int s = l4 * 4 + j;
      atomicAdd(&scal_cur[(b * 8 + s) * 4], pa[j]);
      atomicAdd(&scal_cur[(b * 8 + s) * 4 + 1], px[j]);
      atomicAdd(&scal_cur[(b * 8 + s) * 4 + 2], py[j]);
      atomicAdd(&scal_cur[(b * 8 + s) * 4 + 3], pg[j]);
    }
  }
  __syncthreads();
  // ---- PV: U[slot][dim] += sum_t w'[slot][t] * f[t][dim] ----
  int g32base = chunk >> 5;
  #pragma unroll
  for (int ni = 0; ni < 3; ++ni) {
    int nt = w * 3 + ni;
    f32x4 acc = (f32x4){0.f, 0.f, 0.f, 0.f};
    const u16* vp = fd + ((((long)b * 128 + g32base) * 12 + nt) * 64 + l4 * 16 + l15) * 8;
    #pragma unroll
    for (int gl = 0; gl < 8; ++gl) {
      int tl0 = gl * 32 + l4 * 8;
      bf16x8 afr = *(bf16x8*)((char*)attn_lds + ((l15 * 512 + tl0 * 2) ^ ((l15 & 7) << 4)));
      bf16x8 bfr = *(const bf16x8*)(vp + gl * 12 * 64 * 8);
      acc = __builtin_amdgcn_mfma_f32_16x16x32_bf16(afr, bfr, acc, 0, 0, 0);
    }
    if (l4 < 2) {
      #pragma unroll
      for (int j = 0; j < 4; ++j) {
        int s = l4 * 4 + j;
        atomicAdd(&U[((long)b * 8 + s) * DD + nt * 16 + l15], acc[j]);
      }
    }
  }
}

// ---------------------------------------------------------------------------
// GRU + LN + MLP.  768 threads; first phase computes
// upd = (U - gamma) @ Wvm + asum*s0v, then normalizes by (asum+eps).
// grid (B,4): y0: g0 slot0; y1: g2 slot7; y2: g1 slots1-3; y3: g1 slots4-6.
// ---------------------------------------------------------------------------
template <int M>
__device__ void gru_body(int b0, int g, int srow,
                         float* u_l, float* h_l, float* gi_l, float* gh_l,
                         float* hn_l, float* ln_l, float* x1_l, float* out_l, float* st,
                         const float* __restrict__ U, const float* __restrict__ scal,
                         const float* __restrict__ Wvm, const float* __restrict__ s0v,
                         const float* __restrict__ sin_,
                         const u16* __restrict__ pWih, const u16* __restrict__ pWhh,
                         const float* __restrict__ bih, const float* __restrict__ bhh,
                         const float* __restrict__ mlng, const float* __restrict__ mlnb,
                         const u16* __restrict__ pW1, const float* __restrict__ b1,
                         const u16* __restrict__ pW2, const float* __restrict__ b2,
                         float* __restrict__ sout) {
  int tid = threadIdx.x;
  // stage U rows into hn_l (scratch) + h rows
  for (int idx = tid; idx < M * 192; idx += 768) {
    int row = idx / 192, d = idx % 192;
    int gr = b0 * 8 + srow + row;
    hn_l[row * 192 + d] = U[(long)gr * DD + d];
    h_l[row * 192 + d] = sin_[gr * DD + d];
  }
  __syncthreads();
  // u_l = ((U - gamma) @ Wvm + asum*s0v) / (asum + eps)
  if (tid < M * 192) {
    int row = tid / 192, d = tid % 192;
    int gr = b0 * 8 + srow + row;
    float asum = scal[gr * 4], gam = scal[gr * 4 + 3];
    float inv = 1.f / (asum + 1e-8f);
    float acc = asum * s0v[d];
    const float* ur = hn_l + row * 192;
    #pragma unroll 4
    for (int e = 0; e < DD; ++e) acc += (ur[e] - gam) * Wvm[e * DD + d];
    u_l[row * 192 + d] = acc * inv;
  }
  __syncthreads();
  // GRU gates: thread = output col c of [r|z|n]x192
  if (tid < 576) {
    int c = tid;
    const u16* wih = pWih + (size_t)g * 96 * 1152 + c * 2;
    const u16* whh = pWhh + (size_t)g * 96 * 1152 + c * 2;
    float ai[M], ah[M];
    #pragma unroll
    for (int r = 0; r < M; ++r) { ai[r] = 0.f; ah[r] = 0.f; }
    #pragma unroll 4
    for (int e2 = 0; e2 < 96; ++e2) {
      u32 wi = *(const u32*)(wih + e2 * 1152);
      u32 wh = *(const u32*)(whh + e2 * 1152);
      float wi0 = bf2f(wi & 0xffffu), wi1 = bf2f(wi >> 16);
      float wh0 = bf2f(wh & 0xffffu), wh1 = bf2f(wh >> 16);
      #pragma unroll
      for (int r = 0; r < M; ++r) {
        ai[r] += wi0 * u_l[r * 192 + e2 * 2] + wi1 * u_l[r * 192 + e2 * 2 + 1];
        ah[r] += wh0 * h_l[r * 192 + e2 * 2] + wh1 * h_l[r * 192 + e2 * 2 + 1];
      }
    }
    #pragma unroll
    for (int r = 0; r < M; ++r) { gi_l[r * 576 + c] = ai[r]; gh_l[r * 576 + c] = ah[r]; }
  }
  __syncthreads();
  if (tid < M * 192) {
    int row = tid / 192, uu = tid % 192;
    const float* bihg = bih + g * 576;
    const float* bhhg = bhh + g * 576;
    float r_ = sigm(gi_l[row * 576 + uu] + bihg[uu] + gh_l[row * 576 + uu] + bhhg[uu]);
    float z_ = sigm(gi_l[row * 576 + 192 + uu] + bihg[192 + uu] +
                    gh_l[row * 576 + 192 + uu] + bhhg[192 + uu]);
    float nn = gi_l[row * 576 + 384 + uu] + bihg[384 + uu] +
               r_ * (gh_l[row * 576 + 384 + uu] + bhhg[384 + uu]);
    float t = 1.f - 2.f / (__expf(2.f * nn) + 1.f);
    hn_l[row * 192 + uu] = (1.f - z_) * t + z_ * h_l[row * 192 + uu];
  }
  __syncthreads();
  {
    int wv = tid >> 6, lane = tid & 63;
    if (wv < M) {
      float v0 = hn_l[wv * 192 + lane], v1 = hn_l[wv * 192 + lane + 64],
            v2 = hn_l[wv * 192 + lane + 128];
      float s = v0 + v1 + v2, sq = v0 * v0 + v1 * v1 + v2 * v2;
      #pragma unroll
      for (int m = 1; m < 64; m <<= 1) { s += __shfl_xor(s, m); sq += __shfl_xor(sq, m); }
      if (lane == 0) {
        float mu = s * (1.f / 192.f);
        st[wv * 2] = mu;
        st[wv * 2 + 1] = rsqrtf(sq * (1.f / 192.f) - mu * mu + 1e-5f);
      }
    }
  }
  __syncthreads();
  if (tid < M * 192) {
    int row = tid / 192, uu = tid % 192;
    ln_l[row * 192 + uu] = (hn_l[row * 192 + uu] - st[row * 2]) * st[row * 2 + 1] *
                               mlng[g * DD + uu] + mlnb[g * DD + uu];
  }
  __syncthreads();
  {
    int c = tid;
    const u16* w1 = pW1 + (size_t)g * 96 * 1536 + c * 2;
    float a[M];
    #pragma unroll
    for (int r = 0; r < M; ++r) a[r] = 0.f;
    #pragma unroll 4
    for (int e2 = 0; e2 < 96; ++e2) {
      u32 wp = *(const u32*)(w1 + e2 * 1536);
      float w0 = bf2f(wp & 0xffffu), w1f = bf2f(wp >> 16);
      #pragma unroll
      for (int r = 0; r < M; ++r)
        a[r] += w0 * ln_l[r * 192 + e2 * 2] + w1f * ln_l[r * 192 + e2 * 2 + 1];
    }
    float bc = b1[g * HH + c];
    #pragma unroll
    for (int r = 0; r < M; ++r) x1_l[r * 768 + c] = fmaxf(a[r] + bc, 0.f);
  }
  if (tid < M * 192) {
    int row = tid / 192, uu = tid % 192;
    out_l[row * 192 + uu] = hn_l[row * 192 + uu] + b2[g * DD + uu];
  }
  __syncthreads();
  {
    int c = tid % 192, ks = tid / 192;
    const u16* w2 = pW2 + (size_t)g * 384 * 384 + c * 2;
    float a[M];
    #pragma unroll
    for (int r = 0; r < M; ++r) a[r] = 0.f;
    #pragma unroll 4
    for (int e2 = ks * 96; e2 < ks * 96 + 96; ++e2) {
      u32 wp = *(const u32*)(w2 + e2 * 384);
      float w0 = bf2f(wp & 0xffffu), w1f = bf2f(wp >> 16);
      #pragma unroll
      for (int r = 0; r < M; ++r)
        a[r] += w0 * x1_l[r * 768 + e2 * 2] + w1f * x1_l[r * 768 + e2 * 2 + 1];
    }
    #pragma unroll
    for (int r = 0; r < M; ++r) atomicAdd(&out_l[r * 192 + c], a[r]);
  }
  __syncthreads();
  if (tid < M * 192) {
    int row = tid / 192, d = tid % 192;
    sout[(b0 * 8 + srow + row) * DD + d] = out_l[row * 192 + d];
  }
}

__global__ __launch_bounds__(768) void gru_kernel(
    const float* __restrict__ U, const float* __restrict__ scal,
    const float* __restrict__ Wvm, const float* __restrict__ s0v,
    const float* __restrict__ sin_,
    const u16* __restrict__ pWih, const u16* __restrict__ pWhh,
    const float* __restrict__ bih, const float* __restrict__ bhh,
    const float* __restrict__ mlng, const float* __restrict__ mlnb,
    const u16* __restrict__ pW1, const float* __restrict__ b1,
    const u16* __restrict__ pW2, const float* __restrict__ b2,
    float* __restrict__ sout) {
  __shared__ float u_l[3 * 192], h_l[3 * 192], gi_l[3 * 576], gh_l[3 * 576];
  __shared__ float hn_l[3 * 192], ln_l[3 * 192], x1_l[3 * 768], out_l[3 * 192], st[8];
  int b = blockIdx.x, y = blockIdx.y;
  if (y == 0)
    gru_body<1>(b, 0, 0, u_l, h_l, gi_l, gh_l, hn_l, ln_l, x1_l, out_l, st,
                U, scal, Wvm, s0v, sin_, pWih, pWhh, bih, bhh, mlng, mlnb,
                pW1, b1, pW2, b2, sout);
  else if (y == 1)
    gru_body<1>(b, 2, 7, u_l, h_l, gi_l, gh_l, hn_l, ln_l, x1_l, out_l, st,
                U, scal, Wvm, s0v, sin_, pWih, pWhh, bih, bhh, mlng, mlnb,
                pW1, b1, pW2, b2, sout);
  else if (y == 2)
    gru_body<3>(b, 1, 1, u_l, h_l, gi_l, gh_l, hn_l, ln_l, x1_l, out_l, st,
                U, scal, Wvm, s0v, sin_, pWih, pWhh, bih, bhh, mlng, mlnb,
                pW1, b1, pW2, b2, sout);
  else
    gru_body<3>(b, 1, 4, u_l, h_l, gi_l, gh_l, hn_l, ln_l, x1_l, out_l, st,
                U, scal, Wvm, s0v, sin_, pWih, pWhh, bih, bhh, mlng, mlnb,
                pW1, b1, pW2, b2, sout);
}

// ---------------------------------------------------------------------------
extern "C" void kernel_launch(void* const* d_in, const int* in_sizes, int n_in,
                              void* d_out, int out_size, void* d_ws, size_t ws_size,
                              hipStream_t stream) {
  const float* feat = (const float*)d_in[0];
  const float* slots = (const float*)d_in[1];
  const float* Wk = (const float*)d_in[2];
  const float* Wv = (const float*)d_in[3];
  const float* Wq = (const float*)d_in[4];
  const float* lfg = (const float*)d_in[5];
  const float* lfb = (const float*)d_in[6];
  const float* lsg = (const float*)d_in[7];
  const float* lsb = (const float*)d_in[8];
  const float* gWih = (const float*)d_in[9];
  const float* gWhh = (const float*)d_in[10];
  const float* gbih = (const float*)d_in[11];
  const float* gbhh = (const float*)d_in[12];
  const float* mlng = (const float*)d_in[13];
  const float* mlnb = (const float*)d_in[14];
  const float* W1 = (const float*)d_in[15];
  const float* b1 = (const float*)d_in[16];
  const float* W2 = (const float*)d_in[17];
  const float* b2 = (const float*)d_in[18];
  float* out = (float*)d_out;

  char* ws = (char*)d_ws;
  size_t off = 0;
  auto alloc = [&](size_t bytes) {
    void* p = ws + off;
    off += (bytes + 255) & ~(size_t)255;
    return p;
  };
  u16* fb      = (u16*)alloc((size_t)BB * FF * DD * 2);
  u16* fd      = (u16*)alloc((size_t)BB * DD * FF * 2);
  float2* stats = (float2*)alloc((size_t)BB * FF * 8);
  u16* pbuf    = (u16*)alloc((size_t)BB * 16 * DD * 2);
  float* pab   = (float*)alloc((size_t)BB * 8 * 2 * 4);
  float* U     = (float*)alloc((size_t)BB * 8 * DD * 4);
  float* slA   = (float*)alloc((size_t)BB * 8 * DD * 4);
  float* slB   = (float*)alloc((size_t)BB * 8 * DD * 4);
  float* scal0 = (float*)alloc(BB * 8 * 4 * 4);
  float* scal1 = (float*)alloc(BB * 8 * 4 * 4);
  float* Wvm   = (float*)alloc((size_t)DD * DD * 4);
  float* s0v   = (float*)alloc(DD * 4);
  float* s0k   = (float*)alloc(DD * 4);
  u16* pWih    = (u16*)alloc((size_t)3 * 576 * DD * 2);
  u16* pWhh    = (u16*)alloc((size_t)3 * 576 * DD * 2);
  u16* pW1     = (u16*)alloc((size_t)3 * DD * HH * 2);
  u16* pW2     = (u16*)alloc((size_t)3 * HH * DD * 2);

  prep_vw<<<1, 192, 0, stream>>>(Wk, Wv, lfg, lfb, Wvm, s0v, s0k);
  prep_packw<<<dim3(432, 4), 256, 0, stream>>>(gWih, gWhh, W1, W2, pWih, pWhh, pW1, pW2);
  fconv<<<BB * FF / 64, 256, 0, stream>>>(feat, fb, fd, stats);

  const float* sin_ = slots;
  float* souts[3] = {slA, slB, out};
  float* scals[2] = {scal0, scal1};
  for (int it = 0; it < 3; ++it) {
    int cur = it & 1, prev = cur ^ 1;
    qproj_kernel<<<BB * 8, 64, 0, stream>>>(sin_, Wq, lsg, lsb, Wk, lfg, s0k,
                                            pbuf, pab, U, scals[cur]);
    attnpv_kernel<<<dim3(BB, 16), 256, 0, stream>>>(fb, fd, pbuf, pab, stats,
                                                    scals[prev], U, scals[cur],
                                                    it > 0 ? 1 : 0);
    gru_kernel<<<dim3(BB, 4), 768, 0, stream>>>(U, scals[cur], Wvm, s0v, sin_,
                                                pWih, pWhh, gbih, gbhh, mlng, mlnb,
                                                pW1, b1, pW2, b2, souts[it]);
    sin_ = souts[it];
  }
}